// Round 2
// baseline (554.808 us; speedup 1.0000x reference)
//
#include <hip/hip_runtime.h>
#include <hip/hip_bf16.h>

#define N_SPOKES 524288
#define DIM      128
#define DIM2     256
#define NB       128
#define NH       64
#define BH       8192   // NB*NH

// d_out layout (all float32): [0,1048576) hub_features [8192][128]
//                             [1048576, +2097152) spokes_idx row
//                             [3145728, +2097152) hub ids row
#define OUT_HF   0
#define OUT_E0   1048576
#define OUT_E1   3145728

typedef __attribute__((ext_vector_type(8))) short  short8;
typedef __attribute__((ext_vector_type(4))) float  float4v;
typedef __attribute__((ext_vector_type(4))) unsigned short ushort4v;

__device__ inline unsigned short f2bf(float f) {
    __hip_bfloat16 h = __float2bfloat16(f);
    return *reinterpret_cast<unsigned short*>(&h);
}

// tanh-approx GELU via sigmoid identity
__device__ inline float gelu_f(float v) {
    float s = v * (1.0f + 0.044715f * v * v);
    float e = __builtin_exp2f(-2.302118131f * s);
    return v * __builtin_amdgcn_rcpf(1.0f + e);
}

// ---------- setup: goff + count + W1^T bf16 prep, one kernel ----------
__global__ void setup_kernel(const int* __restrict__ batchidx, const int* __restrict__ hubidx,
                             const float* __restrict__ W1,
                             unsigned short* __restrict__ w1t,
                             int* __restrict__ goff, int* __restrict__ cnt) {
    int b = blockIdx.x, tid = threadIdx.x;
    if (b < 2048) {
        int i = b * 256 + tid;
        if (i < N_SPOKES) {
            int bi = batchidx[i];
            int bp = (i == 0) ? -1 : batchidx[i - 1];
            for (int g = bp + 1; g <= bi; ++g) goff[g] = i;
            if (i == N_SPOKES - 1)
                for (int g = bi + 1; g <= NB; ++g) goff[g] = N_SPOKES;
            atomicAdd(&cnt[bi * NH + hubidx[i]], 1);
        }
    } else {
        int idx = (b - 2048) * 256 + tid;   // 128 blocks -> 32768
        if (idx < DIM * DIM2) {
            int n = idx >> 7, k = idx & 127;
            w1t[idx] = f2bf(W1[k * DIM2 + n]);
        }
    }
}

// ---------- fused FFN + scatter-as-GEMM ----------
// 512 blocks = 128 graphs x 4 chunks, 512 threads (8 waves).
// LDS ~72.7 KB -> 2 blocks/CU -> 16 waves/CU = 4 waves/SIMD (latency hiding).
// Per tile (128 spokes), sliced by ks (32 spokes): main GEMM U-slice =
// gelu(x@W1+b1) via mfma 16x16x32 (32 U-cols/wave); U-slice round-trips LDS
// as bf16 U^T[col][32 rows] (wave-private cols -> no barrier); hub GEMM
// hacc += onehot^T @ U with the one-hot built ONCE per tile in LDS
// (cooperative scatter; each thread clears its own entry after the tile).
// hacc lives in fp32 C-regs across all tiles.
__launch_bounds__(512, 4)
__global__ void ffn_fused(const float* __restrict__ x,
                          const int* __restrict__ hubidx,
                          const int* __restrict__ goff,
                          const unsigned short* __restrict__ w1t,
                          const float* __restrict__ b1,
                          float* __restrict__ outbuf,
                          int atomic_mode) {
    __shared__ unsigned short sA[128 * 136];    // 34816 B  bf16 x tile, row stride 136
    __shared__ unsigned short sU[256 * 40];     // 20480 B  bf16 U^T slice [col][32 rows]
    __shared__ unsigned short sOne[64 * 136];   // 17408 B  one-hot [hub][spoke-in-tile]

    const int tid  = threadIdx.x;
    const int lane = tid & 63;
    const int w    = tid >> 6;          // 0..7
    const int c_lo = lane & 15;
    const int c_hi = lane >> 4;
    const int wcb  = w * 32;            // wave column base (32 cols/wave)
    const int g      = blockIdx.x >> 2;
    const int cchunk = blockIdx.x & 3;

    const int s = goff[g], e = goff[g + 1];
    const int len = e - s;
    const int cs  = (len + 3) >> 2;
    const int ms  = s + cchunk * cs;
    int me = ms + cs; if (me > e) me = e;
    const int n  = me - ms;
    const int nt = (n > 0) ? ((n + 127) >> 7) : 0;

    // W1^T fragments + bias (wave-private cols, L1-resident)
    short8 bfr[2][4];
    #pragma unroll
    for (int n4 = 0; n4 < 2; ++n4)
        #pragma unroll
        for (int k = 0; k < 4; ++k) {
            int col = wcb + n4 * 16 + c_lo;
            bfr[n4][k] = *(const short8*)(w1t + col * DIM + k * 32 + c_hi * 8);
        }
    float bcol[2];
    #pragma unroll
    for (int n4 = 0; n4 < 2; ++n4) bcol[n4] = b1[wcb + n4 * 16 + c_lo];

    // hub accumulator [64 hubs x 32 wave-cols] in fp32 C-regs
    float4v hacc[4][2];
    #pragma unroll
    for (int mt = 0; mt < 4; ++mt)
        #pragma unroll
        for (int n4 = 0; n4 < 2; ++n4) hacc[mt][n4] = (float4v){0.f, 0.f, 0.f, 0.f};

    // zero the one-hot used region [64][128]
    for (int i = tid; i < 2048; i += 512)
        *(unsigned long long*)&sOne[(i >> 5) * 136 + (i & 31) * 4] = 0ULL;

    const float4v* x4 = (const float4v*)x;

    float4v pf[8];
    int hub_nxt = -1;
    if (nt > 0) {
        #pragma unroll
        for (int it = 0; it < 8; ++it) {
            int f = it * 512 + tid;
            int r = f >> 5;
            int rr = r < n ? r : n - 1;
            pf[it] = x4[(size_t)(ms + rr) * 32 + (f & 31)];
        }
        if (tid < 128) hub_nxt = (tid < n) ? hubidx[ms + tid] : -1;
    }
    __syncthreads();   // zero of sOne complete before any scatter

    for (int t = 0; t < nt; ++t) {
        const int hub_cur = hub_nxt;
        // stage prefetched x tile -> sA (f32->bf16)
        #pragma unroll
        for (int it = 0; it < 8; ++it) {
            int f = it * 512 + tid;
            int row = f >> 5, c4 = f & 31;
            float4v v = pf[it];
            ushort4v u = { f2bf(v.x), f2bf(v.y), f2bf(v.z), f2bf(v.w) };
            *(ushort4v*)&sA[row * 136 + c4 * 4] = u;
        }
        if (tid < 128 && hub_cur >= 0)
            sOne[hub_cur * 136 + tid] = (unsigned short)0x3F80;   // bf16 1.0
        __syncthreads();

        // prefetch next tile (fires during compute)
        if (t + 1 < nt) {
            #pragma unroll
            for (int it = 0; it < 8; ++it) {
                int f = it * 512 + tid;
                int r = (t + 1) * 128 + (f >> 5);
                int rr = r < n ? r : n - 1;
                pf[it] = x4[(size_t)(ms + rr) * 32 + (f & 31)];
            }
            if (tid < 128) {
                int r = (t + 1) * 128 + tid;
                hub_nxt = (r < n) ? hubidx[ms + r] : -1;
            }
        }

        // 4 ks-slices of 32 spokes each
        #pragma unroll
        for (int ks = 0; ks < 4; ++ks) {
            // main GEMM slice: U[32 spokes][32 wave-cols]
            float4v acc[2][2];
            #pragma unroll
            for (int m2 = 0; m2 < 2; ++m2)
                #pragma unroll
                for (int n4 = 0; n4 < 2; ++n4) acc[m2][n4] = (float4v){0.f, 0.f, 0.f, 0.f};

            #pragma unroll
            for (int k = 0; k < 4; ++k)
                #pragma unroll
                for (int m2 = 0; m2 < 2; ++m2) {
                    short8 a = *(const short8*)&sA[(ks * 32 + m2 * 16 + c_lo) * 136 + k * 32 + c_hi * 8];
                    acc[m2][0] = __builtin_amdgcn_mfma_f32_16x16x32_bf16(a, bfr[0][k], acc[m2][0], 0, 0, 0);
                    acc[m2][1] = __builtin_amdgcn_mfma_f32_16x16x32_bf16(a, bfr[1][k], acc[m2][1], 0, 0, 0);
                }

            // epilogue: +b1, gelu, write bf16 U^T slice (wave-private cols)
            #pragma unroll
            for (int m2 = 0; m2 < 2; ++m2) {
                int rbase = m2 * 16 + c_hi * 4;
                #pragma unroll
                for (int n4 = 0; n4 < 2; ++n4) {
                    int col = wcb + n4 * 16 + c_lo;
                    float4v a4 = acc[m2][n4];
                    ushort4v u;
                    u.x = f2bf(gelu_f(a4.x + bcol[n4]));
                    u.y = f2bf(gelu_f(a4.y + bcol[n4]));
                    u.z = f2bf(gelu_f(a4.z + bcol[n4]));
                    u.w = f2bf(gelu_f(a4.w + bcol[n4]));
                    *(ushort4v*)&sU[col * 40 + rbase] = u;
                }
            }

            // hub GEMM slice: hacc += onehot^T @ U  (aS from shared one-hot LDS)
            short8 aS[4];
            #pragma unroll
            for (int mt = 0; mt < 4; ++mt)
                aS[mt] = *(const short8*)&sOne[(mt * 16 + c_lo) * 136 + ks * 32 + c_hi * 8];
            short8 bU[2];
            #pragma unroll
            for (int n4 = 0; n4 < 2; ++n4)
                bU[n4] = *(const short8*)&sU[(wcb + n4 * 16 + c_lo) * 40 + c_hi * 8];
            #pragma unroll
            for (int mt = 0; mt < 4; ++mt)
                #pragma unroll
                for (int n4 = 0; n4 < 2; ++n4)
                    hacc[mt][n4] = __builtin_amdgcn_mfma_f32_16x16x32_bf16(aS[mt], bU[n4], hacc[mt][n4], 0, 0, 0);
        }
        __syncthreads();
        // clear own one-hot entry (ordered vs next tile's reads by barrier1)
        if (tid < 128 && hub_cur >= 0)
            sOne[hub_cur * 136 + tid] = 0;
    }

    // flush: hub = mt*16 + c_hi*4 + reg, col = wcb + n4*16 + c_lo
    #pragma unroll
    for (int mt = 0; mt < 4; ++mt)
        #pragma unroll
        for (int n4 = 0; n4 < 2; ++n4) {
            float4v v = hacc[mt][n4];
            int col = wcb + n4 * 16 + c_lo;
            #pragma unroll
            for (int reg = 0; reg < 4; ++reg) {
                int hub = mt * 16 + c_hi * 4 + reg;
                size_t o = ((size_t)g * NH + hub) * DIM2 + col;
                if (atomic_mode) atomicAdd(&outbuf[o], v[reg]);
                else outbuf[(size_t)cchunk * BH * DIM2 + o] = v[reg];
            }
        }
}

// ---------- hub_features = (hubsum@W2 + cnt*b2) / max(cnt,1) ----------
__global__ void hubfeat_kernel(const float* __restrict__ part, int nchunk,
                               const int* __restrict__ cnt,
                               const float* __restrict__ W2, const float* __restrict__ b2,
                               float* __restrict__ out) {
    __shared__ float sSum[16 * 256];
    int tid = threadIdx.x;
    int d   = tid & 127;
    int hh  = tid >> 7;

    for (int i = tid; i < 16 * 256; i += 256) {
        size_t o = (size_t)(blockIdx.x * 16) * DIM2 + i;
        float v = 0.f;
        for (int c = 0; c < nchunk; ++c) v += part[(size_t)c * BH * DIM2 + o];
        sSum[i] = v;
    }
    __syncthreads();

    int h0 = hh * 8;
    float acc[8] = {0.f, 0.f, 0.f, 0.f, 0.f, 0.f, 0.f, 0.f};
    for (int k4 = 0; k4 < 64; ++k4) {
        float w0 = W2[(k4 * 4 + 0) * DIM + d];
        float w1 = W2[(k4 * 4 + 1) * DIM + d];
        float w2 = W2[(k4 * 4 + 2) * DIM + d];
        float w3 = W2[(k4 * 4 + 3) * DIM + d];
        #pragma unroll
        for (int j = 0; j < 8; ++j) {
            float4v sv = *(const float4v*)&sSum[(h0 + j) * 256 + k4 * 4];
            acc[j] += sv.x * w0 + sv.y * w1 + sv.z * w2 + sv.w * w3;
        }
    }
    float b2d = b2[d];
    #pragma unroll
    for (int j = 0; j < 8; ++j) {
        int h = blockIdx.x * 16 + h0 + j;
        float c = (float)cnt[h];
        out[OUT_HF + h * DIM + d] = (acc[j] + c * b2d) / fmaxf(c, 1.0f);
    }
}

// ---------- per-graph KNN + edge emission (merged) ----------
__global__ void knn_edges(const float* __restrict__ hf, const int* __restrict__ goff,
                          const int* __restrict__ hubidx, float* __restrict__ out) {
    __shared__ float s[64 * 129];
    __shared__ float d2[64 * 64];
    __shared__ int sK[64 * 4];
    int g = blockIdx.x, tid = threadIdx.x;

    for (int i = tid; i < 64 * 128; i += 256) {
        int r = i >> 7, c = i & 127;
        s[r * 129 + c] = hf[OUT_HF + (g * 64 + r) * DIM + c];
    }
    __syncthreads();

    for (int p = tid; p < 4096; p += 256) {
        int i = p >> 6, j = p & 63;
        float a = 0.f;
        for (int k = 0; k < 128; ++k) {
            float dd = s[i * 129 + k] - s[j * 129 + k];
            a += dd * dd;
        }
        d2[p] = a;
    }
    __syncthreads();

    if (tid < 64) {
        float bv0 = 1e30f, bv1 = 1e30f, bv2 = 1e30f, bv3 = 1e30f;
        int   bi0 = 0,     bi1 = 0,     bi2 = 0,     bi3 = 0;
        for (int j = 0; j < 64; ++j) {
            float v = d2[tid * 64 + j];
            if (v < bv0)      { bv3=bv2; bi3=bi2; bv2=bv1; bi2=bi1; bv1=bv0; bi1=bi0; bv0=v; bi0=j; }
            else if (v < bv1) { bv3=bv2; bi3=bi2; bv2=bv1; bi2=bi1; bv1=v;   bi1=j; }
            else if (v < bv2) { bv3=bv2; bi3=bi2; bv2=v;   bi2=j; }
            else if (v < bv3) { bv3=v;   bi3=j; }
        }
        sK[tid * 4 + 0] = bi0; sK[tid * 4 + 1] = bi1;
        sK[tid * 4 + 2] = bi2; sK[tid * 4 + 3] = bi3;
    }
    __syncthreads();

    int sgs = goff[g], sge = goff[g + 1];
    float gbase = (float)(g * NH);
    for (int i = sgs + tid; i < sge; i += 256) {
        int h = hubidx[i];
        int4 kn = *(const int4*)&sK[h * 4];
        float fi = (float)i;
        float4v o0 = { fi, fi, fi, fi };
        ((float4v*)(out + OUT_E0))[i] = o0;
        float4v o1 = { kn.x + gbase, kn.y + gbase, kn.z + gbase, kn.w + gbase };
        ((float4v*)(out + OUT_E1))[i] = o1;
    }
}

extern "C" void kernel_launch(void* const* d_in, const int* in_sizes, int n_in,
                              void* d_out, int out_size, void* d_ws, size_t ws_size,
                              hipStream_t stream) {
    const float* x        = (const float*)d_in[0];
    const int*   hubidx   = (const int*)d_in[1];
    const int*   batchidx = (const int*)d_in[2];
    const float* W1       = (const float*)d_in[3];
    const float* b1       = (const float*)d_in[4];
    const float* W2       = (const float*)d_in[5];
    const float* b2       = (const float*)d_in[6];
    float* out = (float*)d_out;
    char*  ws  = (char*)d_ws;

    // 4-partial mode: 4 x 8MB part + cnt + w1t + goff
    const size_t need_partial = 33654784;
    int atomic_mode = (ws_size < need_partial) ? 1 : 0;

    float*          part;
    int*            cnt;
    unsigned short* w1t;
    int*            goff;
    if (!atomic_mode) {
        part = (float*)ws;                          // 33554432 B (4 x 8MB)
        cnt  = (int*)(ws + 33554432);               // 32768 B
        w1t  = (unsigned short*)(ws + 33587200);    // 65536 B
        goff = (int*)(ws + 33652736);               // 2048 B
    } else {
        part = (float*)ws;                          // 8388608 B
        cnt  = (int*)(ws + 8388608);
        w1t  = (unsigned short*)(ws + 8421376);
        goff = (int*)(ws + 8486912);
    }

    (void)hipMemsetAsync(cnt, 0, 32768, stream);
    if (atomic_mode) (void)hipMemsetAsync(part, 0, 8388608, stream);

    setup_kernel<<<2176, 256, 0, stream>>>(batchidx, hubidx, W1, w1t, goff, cnt);
    ffn_fused   <<<512,  512, 0, stream>>>(x, hubidx, goff, w1t, b1, part, atomic_mode);
    hubfeat_kernel<<<512, 256, 0, stream>>>(part, atomic_mode ? 1 : 4, cnt, W2, b2, out);
    knn_edges   <<<NB,   256, 0, stream>>>(out, goff, hubidx, out);
}

// Round 3
// 516.832 us; speedup vs baseline: 1.0735x; 1.0735x over previous
//
#include <hip/hip_runtime.h>
#include <hip/hip_bf16.h>

#define N_SPOKES 524288
#define DIM      128
#define DIM2     256
#define NB       128
#define NH       64
#define BH       8192   // NB*NH

// d_out layout (all float32): [0,1048576) hub_features [8192][128]
//                             [1048576, +2097152) spokes_idx row
//                             [3145728, +2097152) hub ids row
#define OUT_HF   0
#define OUT_E0   1048576
#define OUT_E1   3145728

typedef __attribute__((ext_vector_type(8))) short  short8;
typedef __attribute__((ext_vector_type(4))) float  float4v;
typedef __attribute__((ext_vector_type(4))) unsigned short ushort4v;

__device__ inline unsigned short f2bf(float f) {
    __hip_bfloat16 h = __float2bfloat16(f);
    return *reinterpret_cast<unsigned short*>(&h);
}

// packed f32x2 -> bf16x2 (v_cvt_pk_bf16_f32)
__device__ inline unsigned int pkbf(float a, float b) {
    __hip_bfloat162 h = __float22bfloat162_rn(make_float2(a, b));
    union { __hip_bfloat162 h; unsigned int u; } cv;
    cv.h = h;
    return cv.u;
}

// tanh-approx GELU via sigmoid identity
__device__ inline float gelu_f(float v) {
    float s = v * (1.0f + 0.044715f * v * v);
    float e = __builtin_exp2f(-2.302118131f * s);
    return v * __builtin_amdgcn_rcpf(1.0f + e);
}

// ---------- setup: goff + count + W1^T bf16 prep, one kernel ----------
__global__ void setup_kernel(const int* __restrict__ batchidx, const int* __restrict__ hubidx,
                             const float* __restrict__ W1,
                             unsigned short* __restrict__ w1t,
                             int* __restrict__ goff, int* __restrict__ cnt) {
    int b = blockIdx.x, tid = threadIdx.x;
    if (b < 2048) {
        int i = b * 256 + tid;
        if (i < N_SPOKES) {
            int bi = batchidx[i];
            int bp = (i == 0) ? -1 : batchidx[i - 1];
            for (int g = bp + 1; g <= bi; ++g) goff[g] = i;
            if (i == N_SPOKES - 1)
                for (int g = bi + 1; g <= NB; ++g) goff[g] = N_SPOKES;
            atomicAdd(&cnt[bi * NH + hubidx[i]], 1);
        }
    } else {
        int idx = (b - 2048) * 256 + tid;   // 128 blocks -> 32768
        if (idx < DIM * DIM2) {
            int n = idx >> 7, k = idx & 127;
            w1t[idx] = f2bf(W1[k * DIM2 + n]);
        }
    }
}

// ---------- fused FFN + scatter-as-GEMM ----------
// 512 blocks = 128 graphs x 4 chunks, 512 threads (8 waves).
// LDS 72704 B -> 2 blocks/CU -> 16 waves/CU = 4 waves/SIMD.
// Register discipline for the 128-reg cap (round-2 lesson: pf[8] held across
// compute spilled to scratch): x loads are a burst at the TOP of the staging
// phase, consumed immediately -> 32 regs live only inside staging, never
// concurrent with compute temps.  The exposed HBM wait is covered by the
// co-resident second block.  Packed bf16 cvt halves conversion VALU.
__launch_bounds__(512, 4)
__global__ void ffn_fused(const float* __restrict__ x,
                          const int* __restrict__ hubidx,
                          const int* __restrict__ goff,
                          const unsigned short* __restrict__ w1t,
                          const float* __restrict__ b1,
                          float* __restrict__ outbuf,
                          int atomic_mode) {
    __shared__ unsigned short sA[128 * 136];    // 34816 B  bf16 x tile, row stride 136
    __shared__ unsigned short sU[256 * 40];     // 20480 B  bf16 U^T slice [col][32 rows]
    __shared__ unsigned short sOne[64 * 136];   // 17408 B  one-hot [hub][spoke-in-tile]

    const int tid  = threadIdx.x;
    const int lane = tid & 63;
    const int w    = tid >> 6;          // 0..7
    const int c_lo = lane & 15;
    const int c_hi = lane >> 4;
    const int wcb  = w * 32;            // wave column base (32 cols/wave)
    const int g      = blockIdx.x >> 2;
    const int cchunk = blockIdx.x & 3;

    const int s = goff[g], e = goff[g + 1];
    const int len = e - s;
    const int cs  = (len + 3) >> 2;
    const int ms  = s + cchunk * cs;
    int me = ms + cs; if (me > e) me = e;
    const int n  = me - ms;
    const int nt = (n > 0) ? ((n + 127) >> 7) : 0;

    // W1^T fragments + bias (wave-private cols, L1-resident)
    short8 bfr[2][4];
    #pragma unroll
    for (int n4 = 0; n4 < 2; ++n4)
        #pragma unroll
        for (int k = 0; k < 4; ++k) {
            int col = wcb + n4 * 16 + c_lo;
            bfr[n4][k] = *(const short8*)(w1t + col * DIM + k * 32 + c_hi * 8);
        }
    float bcol[2];
    #pragma unroll
    for (int n4 = 0; n4 < 2; ++n4) bcol[n4] = b1[wcb + n4 * 16 + c_lo];

    // hub accumulator [64 hubs x 32 wave-cols] in fp32 C-regs
    float4v hacc[4][2];
    #pragma unroll
    for (int mt = 0; mt < 4; ++mt)
        #pragma unroll
        for (int n4 = 0; n4 < 2; ++n4) hacc[mt][n4] = (float4v){0.f, 0.f, 0.f, 0.f};

    // zero the one-hot used region [64][128]
    for (int i = tid; i < 2048; i += 512)
        *(unsigned long long*)&sOne[(i >> 5) * 136 + (i & 31) * 4] = 0ULL;

    const float4v* x4 = (const float4v*)x;

    int hub_nxt = -1;
    if (nt > 0 && tid < 128) hub_nxt = (tid < n) ? hubidx[ms + tid] : -1;
    __syncthreads();   // zero of sOne complete before any scatter

    for (int t = 0; t < nt; ++t) {
        const int hub_cur = hub_nxt;

        // ---- staging phase: burst-load this tile's x, cvt, write sA ----
        {
            float4v ld[8];
            #pragma unroll
            for (int it = 0; it < 8; ++it) {
                int f = it * 512 + tid;
                int r = t * 128 + (f >> 5);
                int rr = r < n ? r : n - 1;
                ld[it] = x4[(size_t)(ms + rr) * 32 + (f & 31)];
            }
            // one-hot scatter rides the load latency
            if (tid < 128 && hub_cur >= 0)
                sOne[hub_cur * 136 + tid] = (unsigned short)0x3F80;   // bf16 1.0
            #pragma unroll
            for (int it = 0; it < 8; ++it) {
                int f = it * 512 + tid;
                int row = f >> 5, c4 = f & 31;
                float4v v = ld[it];
                unsigned int lo = pkbf(v.x, v.y);
                unsigned int hi = pkbf(v.z, v.w);
                *(uint2*)&sA[row * 136 + c4 * 4] = make_uint2(lo, hi);
            }
        }
        __syncthreads();

        // prefetch next tile's hub ids (1 reg, latency-tolerant)
        if (t + 1 < nt && tid < 128) {
            int r = (t + 1) * 128 + tid;
            hub_nxt = (r < n) ? hubidx[ms + r] : -1;
        }

        // ---- compute: 4 ks-slices of 32 spokes each ----
        #pragma unroll
        for (int ks = 0; ks < 4; ++ks) {
            // main GEMM slice: U[32 spokes][32 wave-cols]
            float4v acc[2][2];
            #pragma unroll
            for (int m2 = 0; m2 < 2; ++m2)
                #pragma unroll
                for (int n4 = 0; n4 < 2; ++n4) acc[m2][n4] = (float4v){0.f, 0.f, 0.f, 0.f};

            #pragma unroll
            for (int k = 0; k < 4; ++k)
                #pragma unroll
                for (int m2 = 0; m2 < 2; ++m2) {
                    short8 a = *(const short8*)&sA[(ks * 32 + m2 * 16 + c_lo) * 136 + k * 32 + c_hi * 8];
                    acc[m2][0] = __builtin_amdgcn_mfma_f32_16x16x32_bf16(a, bfr[0][k], acc[m2][0], 0, 0, 0);
                    acc[m2][1] = __builtin_amdgcn_mfma_f32_16x16x32_bf16(a, bfr[1][k], acc[m2][1], 0, 0, 0);
                }

            // epilogue: +b1, gelu, packed-cvt, write bf16 U^T slice (wave-private cols)
            #pragma unroll
            for (int m2 = 0; m2 < 2; ++m2) {
                int rbase = m2 * 16 + c_hi * 4;
                #pragma unroll
                for (int n4 = 0; n4 < 2; ++n4) {
                    int col = wcb + n4 * 16 + c_lo;
                    float4v a4 = acc[m2][n4];
                    unsigned int lo = pkbf(gelu_f(a4.x + bcol[n4]), gelu_f(a4.y + bcol[n4]));
                    unsigned int hi = pkbf(gelu_f(a4.z + bcol[n4]), gelu_f(a4.w + bcol[n4]));
                    *(uint2*)&sU[col * 40 + rbase] = make_uint2(lo, hi);
                }
            }

            // hub GEMM slice: hacc += onehot^T @ U  (aS from shared one-hot LDS)
            short8 aS[4];
            #pragma unroll
            for (int mt = 0; mt < 4; ++mt)
                aS[mt] = *(const short8*)&sOne[(mt * 16 + c_lo) * 136 + ks * 32 + c_hi * 8];
            short8 bU[2];
            #pragma unroll
            for (int n4 = 0; n4 < 2; ++n4)
                bU[n4] = *(const short8*)&sU[(wcb + n4 * 16 + c_lo) * 40 + c_hi * 8];
            #pragma unroll
            for (int mt = 0; mt < 4; ++mt)
                #pragma unroll
                for (int n4 = 0; n4 < 2; ++n4)
                    hacc[mt][n4] = __builtin_amdgcn_mfma_f32_16x16x32_bf16(aS[mt], bU[n4], hacc[mt][n4], 0, 0, 0);
        }
        __syncthreads();
        // clear own one-hot entry (ordered vs next tile's reads by barrier1)
        if (tid < 128 && hub_cur >= 0)
            sOne[hub_cur * 136 + tid] = 0;
    }

    // flush: hub = mt*16 + c_hi*4 + reg, col = wcb + n4*16 + c_lo
    #pragma unroll
    for (int mt = 0; mt < 4; ++mt)
        #pragma unroll
        for (int n4 = 0; n4 < 2; ++n4) {
            float4v v = hacc[mt][n4];
            int col = wcb + n4 * 16 + c_lo;
            #pragma unroll
            for (int reg = 0; reg < 4; ++reg) {
                int hub = mt * 16 + c_hi * 4 + reg;
                size_t o = ((size_t)g * NH + hub) * DIM2 + col;
                if (atomic_mode) atomicAdd(&outbuf[o], v[reg]);
                else outbuf[(size_t)cchunk * BH * DIM2 + o] = v[reg];
            }
        }
}

// ---------- hub_features = (hubsum@W2 + cnt*b2) / max(cnt,1) ----------
__global__ void hubfeat_kernel(const float* __restrict__ part, int nchunk,
                               const int* __restrict__ cnt,
                               const float* __restrict__ W2, const float* __restrict__ b2,
                               float* __restrict__ out) {
    __shared__ float sSum[16 * 256];
    int tid = threadIdx.x;
    int d   = tid & 127;
    int hh  = tid >> 7;

    for (int i = tid; i < 16 * 256; i += 256) {
        size_t o = (size_t)(blockIdx.x * 16) * DIM2 + i;
        float v = 0.f;
        for (int c = 0; c < nchunk; ++c) v += part[(size_t)c * BH * DIM2 + o];
        sSum[i] = v;
    }
    __syncthreads();

    int h0 = hh * 8;
    float acc[8] = {0.f, 0.f, 0.f, 0.f, 0.f, 0.f, 0.f, 0.f};
    for (int k4 = 0; k4 < 64; ++k4) {
        float w0 = W2[(k4 * 4 + 0) * DIM + d];
        float w1 = W2[(k4 * 4 + 1) * DIM + d];
        float w2 = W2[(k4 * 4 + 2) * DIM + d];
        float w3 = W2[(k4 * 4 + 3) * DIM + d];
        #pragma unroll
        for (int j = 0; j < 8; ++j) {
            float4v sv = *(const float4v*)&sSum[(h0 + j) * 256 + k4 * 4];
            acc[j] += sv.x * w0 + sv.y * w1 + sv.z * w2 + sv.w * w3;
        }
    }
    float b2d = b2[d];
    #pragma unroll
    for (int j = 0; j < 8; ++j) {
        int h = blockIdx.x * 16 + h0 + j;
        float c = (float)cnt[h];
        out[OUT_HF + h * DIM + d] = (acc[j] + c * b2d) / fmaxf(c, 1.0f);
    }
}

// ---------- per-graph KNN + edge emission (merged) ----------
__global__ void knn_edges(const float* __restrict__ hf, const int* __restrict__ goff,
                          const int* __restrict__ hubidx, float* __restrict__ out) {
    __shared__ float s[64 * 129];
    __shared__ float d2[64 * 64];
    __shared__ int sK[64 * 4];
    int g = blockIdx.x, tid = threadIdx.x;

    for (int i = tid; i < 64 * 128; i += 256) {
        int r = i >> 7, c = i & 127;
        s[r * 129 + c] = hf[OUT_HF + (g * 64 + r) * DIM + c];
    }
    __syncthreads();

    for (int p = tid; p < 4096; p += 256) {
        int i = p >> 6, j = p & 63;
        float a = 0.f;
        for (int k = 0; k < 128; ++k) {
            float dd = s[i * 129 + k] - s[j * 129 + k];
            a += dd * dd;
        }
        d2[p] = a;
    }
    __syncthreads();

    if (tid < 64) {
        float bv0 = 1e30f, bv1 = 1e30f, bv2 = 1e30f, bv3 = 1e30f;
        int   bi0 = 0,     bi1 = 0,     bi2 = 0,     bi3 = 0;
        for (int j = 0; j < 64; ++j) {
            float v = d2[tid * 64 + j];
            if (v < bv0)      { bv3=bv2; bi3=bi2; bv2=bv1; bi2=bi1; bv1=bv0; bi1=bi0; bv0=v; bi0=j; }
            else if (v < bv1) { bv3=bv2; bi3=bi2; bv2=bv1; bi2=bi1; bv1=v;   bi1=j; }
            else if (v < bv2) { bv3=bv2; bi3=bi2; bv2=v;   bi2=j; }
            else if (v < bv3) { bv3=v;   bi3=j; }
        }
        sK[tid * 4 + 0] = bi0; sK[tid * 4 + 1] = bi1;
        sK[tid * 4 + 2] = bi2; sK[tid * 4 + 3] = bi3;
    }
    __syncthreads();

    int sgs = goff[g], sge = goff[g + 1];
    float gbase = (float)(g * NH);
    for (int i = sgs + tid; i < sge; i += 256) {
        int h = hubidx[i];
        int4 kn = *(const int4*)&sK[h * 4];
        float fi = (float)i;
        float4v o0 = { fi, fi, fi, fi };
        ((float4v*)(out + OUT_E0))[i] = o0;
        float4v o1 = { kn.x + gbase, kn.y + gbase, kn.z + gbase, kn.w + gbase };
        ((float4v*)(out + OUT_E1))[i] = o1;
    }
}

extern "C" void kernel_launch(void* const* d_in, const int* in_sizes, int n_in,
                              void* d_out, int out_size, void* d_ws, size_t ws_size,
                              hipStream_t stream) {
    const float* x        = (const float*)d_in[0];
    const int*   hubidx   = (const int*)d_in[1];
    const int*   batchidx = (const int*)d_in[2];
    const float* W1       = (const float*)d_in[3];
    const float* b1       = (const float*)d_in[4];
    const float* W2       = (const float*)d_in[5];
    const float* b2       = (const float*)d_in[6];
    float* out = (float*)d_out;
    char*  ws  = (char*)d_ws;

    // 4-partial mode: 4 x 8MB part + cnt + w1t + goff
    const size_t need_partial = 33654784;
    int atomic_mode = (ws_size < need_partial) ? 1 : 0;

    float*          part;
    int*            cnt;
    unsigned short* w1t;
    int*            goff;
    if (!atomic_mode) {
        part = (float*)ws;                          // 33554432 B (4 x 8MB)
        cnt  = (int*)(ws + 33554432);               // 32768 B
        w1t  = (unsigned short*)(ws + 33587200);    // 65536 B
        goff = (int*)(ws + 33652736);               // 2048 B
    } else {
        part = (float*)ws;                          // 8388608 B
        cnt  = (int*)(ws + 8388608);
        w1t  = (unsigned short*)(ws + 8421376);
        goff = (int*)(ws + 8486912);
    }

    (void)hipMemsetAsync(cnt, 0, 32768, stream);
    if (atomic_mode) (void)hipMemsetAsync(part, 0, 8388608, stream);

    setup_kernel<<<2176, 256, 0, stream>>>(batchidx, hubidx, W1, w1t, goff, cnt);
    ffn_fused   <<<512,  512, 0, stream>>>(x, hubidx, goff, w1t, b1, part, atomic_mode);
    hubfeat_kernel<<<512, 256, 0, stream>>>(part, atomic_mode ? 1 : 4, cnt, W2, b2, out);
    knn_edges   <<<NB,   256, 0, stream>>>(out, goff, hubidx, out);
}

// Round 4
// 492.770 us; speedup vs baseline: 1.1259x; 1.0488x over previous
//
#include <hip/hip_runtime.h>
#include <hip/hip_bf16.h>

#define N_SPOKES 524288
#define DIM      128
#define DIM2     256
#define NB       128
#define NH       64
#define BH       8192   // NB*NH

// d_out layout (all float32): [0,1048576) hub_features [8192][128]
//                             [1048576, +2097152) spokes_idx row
//                             [3145728, +2097152) hub ids row
#define OUT_HF   0
#define OUT_E0   1048576
#define OUT_E1   3145728

typedef __attribute__((ext_vector_type(8))) short  short8;
typedef __attribute__((ext_vector_type(4))) float  float4v;
typedef __attribute__((ext_vector_type(4))) unsigned short ushort4v;

__device__ inline unsigned short f2bf(float f) {
    __hip_bfloat16 h = __float2bfloat16(f);
    return *reinterpret_cast<unsigned short*>(&h);
}

// packed f32x2 -> bf16x2 (v_cvt_pk_bf16_f32)
__device__ inline unsigned int pkbf(float a, float b) {
    __hip_bfloat162 h = __float22bfloat162_rn(make_float2(a, b));
    union { __hip_bfloat162 h; unsigned int u; } cv;
    cv.h = h;
    return cv.u;
}

// tanh-approx GELU via sigmoid identity
__device__ inline float gelu_f(float v) {
    float s = v * (1.0f + 0.044715f * v * v);
    float e = __builtin_exp2f(-2.302118131f * s);
    return v * __builtin_amdgcn_rcpf(1.0f + e);
}

// ---------- setup: goff + count + W1^T bf16 prep, one kernel ----------
__global__ void setup_kernel(const int* __restrict__ batchidx, const int* __restrict__ hubidx,
                             const float* __restrict__ W1,
                             unsigned short* __restrict__ w1t,
                             int* __restrict__ goff, int* __restrict__ cnt) {
    int b = blockIdx.x, tid = threadIdx.x;
    if (b < 2048) {
        int i = b * 256 + tid;
        if (i < N_SPOKES) {
            int bi = batchidx[i];
            int bp = (i == 0) ? -1 : batchidx[i - 1];
            for (int g = bp + 1; g <= bi; ++g) goff[g] = i;
            if (i == N_SPOKES - 1)
                for (int g = bi + 1; g <= NB; ++g) goff[g] = N_SPOKES;
            atomicAdd(&cnt[bi * NH + hubidx[i]], 1);
        }
    } else {
        int idx = (b - 2048) * 256 + tid;   // 128 blocks -> 32768
        if (idx < DIM * DIM2) {
            int n = idx >> 7, k = idx & 127;
            w1t[idx] = f2bf(W1[k * DIM2 + n]);
        }
    }
}

// ---------- fused FFN + scatter-as-GEMM ----------
// 256 blocks = 128 graphs x 2 chunks, 512 threads (8 waves), 1 block/CU.
// LDS 124928 B: sA[2], sOne[2] double-buffered -> ONE barrier per tile.
// Pipeline (BW-saturation fix): tile t+1's x loads are ISSUED right AFTER the
// barrier (a load issued before __syncthreads is killed by the compiler's
// vmcnt(0) drain at the barrier) and stay in flight across the whole compute
// phase -> memory system continuously busy instead of ~30% duty cycle.
// ld[8] (32 VGPR) lives across compute: needs the 256-reg cap of
// __launch_bounds__(512,2) -- at (512,4)'s 128-reg cap this spilled (round 2).
// Per tile: stage p=t&1 (clear t-2 one-hot entry, scatter t, cvt ld->sA[p]);
// barrier; issue ld(t+1); compute 4 ks-slices from sA[p]/sOne[p]
// (main MFMA -> gelu -> wave-private sU round-trip -> hub MFMA into hacc).
__launch_bounds__(512, 2)
__global__ void ffn_fused(const float* __restrict__ x,
                          const int* __restrict__ hubidx,
                          const int* __restrict__ goff,
                          const unsigned short* __restrict__ w1t,
                          const float* __restrict__ b1,
                          float* __restrict__ outbuf,
                          int atomic_mode) {
    __shared__ unsigned short sA[2][128 * 136];    // 2 x 34816 B  bf16 x tile
    __shared__ unsigned short sU[256 * 40];        // 20480 B  bf16 U^T slice
    __shared__ unsigned short sOne[2][64 * 136];   // 2 x 17408 B  one-hot

    const int tid  = threadIdx.x;
    const int lane = tid & 63;
    const int w    = tid >> 6;          // 0..7
    const int c_lo = lane & 15;
    const int c_hi = lane >> 4;
    const int wcb  = w * 32;            // wave column base (32 cols/wave)
    const int g      = blockIdx.x >> 1;
    const int cchunk = blockIdx.x & 1;

    const int s = goff[g], e = goff[g + 1];
    const int len = e - s;
    const int cs  = (len + 1) >> 1;
    const int ms  = s + cchunk * cs;
    int me = ms + cs; if (me > e) me = e;
    const int n  = me - ms;
    const int nt = (n > 0) ? ((n + 127) >> 7) : 0;

    // W1^T fragments + bias (wave-private cols, L1-resident)
    short8 bfr[2][4];
    #pragma unroll
    for (int n4 = 0; n4 < 2; ++n4)
        #pragma unroll
        for (int k = 0; k < 4; ++k) {
            int col = wcb + n4 * 16 + c_lo;
            bfr[n4][k] = *(const short8*)(w1t + col * DIM + k * 32 + c_hi * 8);
        }
    float bcol[2];
    #pragma unroll
    for (int n4 = 0; n4 < 2; ++n4) bcol[n4] = b1[wcb + n4 * 16 + c_lo];

    // hub accumulator [64 hubs x 32 wave-cols] in fp32 C-regs
    float4v hacc[4][2];
    #pragma unroll
    for (int mt = 0; mt < 4; ++mt)
        #pragma unroll
        for (int n4 = 0; n4 < 2; ++n4) hacc[mt][n4] = (float4v){0.f, 0.f, 0.f, 0.f};

    // zero both one-hot buffers' used region [64][128]
    for (int i = tid; i < 4096; i += 512) {
        int b = i >> 11, r = (i >> 5) & 63, c = i & 31;
        *(unsigned long long*)&sOne[b][r * 136 + c * 4] = 0ULL;
    }

    const float4v* x4 = (const float4v*)x;

    float4v ld[8];
    int hub_nxt = -1;
    int hubA = -1, hubB = -1;   // hub scattered most recently into parity 0 / 1
    if (nt > 0) {
        #pragma unroll
        for (int it = 0; it < 8; ++it) {
            int f = it * 512 + tid;
            int r = f >> 5;
            int rr = r < n ? r : n - 1;
            ld[it] = x4[(size_t)(ms + rr) * 32 + (f & 31)];
        }
        if (tid < 128) hub_nxt = (tid < n) ? hubidx[ms + tid] : -1;
    }
    __syncthreads();   // sOne zeroing complete

    for (int t = 0; t < nt; ++t) {
        const int p = t & 1;
        const int hub_cur = hub_nxt;
        const int hclear  = p ? hubB : hubA;

        // ---- stage phase into parity-p buffers ----
        // one-hot maintenance rides the vmcnt wait for ld
        if (tid < 128) {
            if (hclear >= 0)  sOne[p][hclear * 136 + tid] = 0;
            if (hub_cur >= 0) sOne[p][hub_cur * 136 + tid] = (unsigned short)0x3F80;
        }
        if (p) hubB = hub_cur; else hubA = hub_cur;

        #pragma unroll
        for (int it = 0; it < 8; ++it) {
            int f = it * 512 + tid;
            int row = f >> 5, c4 = f & 31;
            float4v v = ld[it];
            unsigned int lo = pkbf(v.x, v.y);
            unsigned int hi = pkbf(v.z, v.w);
            *(uint2*)&sA[p][row * 136 + c4 * 4] = make_uint2(lo, hi);
        }
        __syncthreads();

        // ---- issue next tile's loads (AFTER barrier: stays in flight
        //      across the whole compute phase) ----
        if (t + 1 < nt) {
            #pragma unroll
            for (int it = 0; it < 8; ++it) {
                int f = it * 512 + tid;
                int r = (t + 1) * 128 + (f >> 5);
                int rr = r < n ? r : n - 1;
                ld[it] = x4[(size_t)(ms + rr) * 32 + (f & 31)];
            }
            if (tid < 128) {
                int r = (t + 1) * 128 + tid;
                hub_nxt = (r < n) ? hubidx[ms + r] : -1;
            }
        }

        // ---- compute: 4 ks-slices of 32 spokes each ----
        #pragma unroll
        for (int ks = 0; ks < 4; ++ks) {
            // main GEMM slice: U[32 spokes][32 wave-cols]
            float4v acc[2][2];
            #pragma unroll
            for (int m2 = 0; m2 < 2; ++m2)
                #pragma unroll
                for (int n4 = 0; n4 < 2; ++n4) acc[m2][n4] = (float4v){0.f, 0.f, 0.f, 0.f};

            #pragma unroll
            for (int k = 0; k < 4; ++k)
                #pragma unroll
                for (int m2 = 0; m2 < 2; ++m2) {
                    short8 a = *(const short8*)&sA[p][(ks * 32 + m2 * 16 + c_lo) * 136 + k * 32 + c_hi * 8];
                    acc[m2][0] = __builtin_amdgcn_mfma_f32_16x16x32_bf16(a, bfr[0][k], acc[m2][0], 0, 0, 0);
                    acc[m2][1] = __builtin_amdgcn_mfma_f32_16x16x32_bf16(a, bfr[1][k], acc[m2][1], 0, 0, 0);
                }

            // epilogue: +b1, gelu, packed-cvt, write bf16 U^T slice (wave-private cols)
            #pragma unroll
            for (int m2 = 0; m2 < 2; ++m2) {
                int rbase = m2 * 16 + c_hi * 4;
                #pragma unroll
                for (int n4 = 0; n4 < 2; ++n4) {
                    int col = wcb + n4 * 16 + c_lo;
                    float4v a4 = acc[m2][n4];
                    unsigned int lo = pkbf(gelu_f(a4.x + bcol[n4]), gelu_f(a4.y + bcol[n4]));
                    unsigned int hi = pkbf(gelu_f(a4.z + bcol[n4]), gelu_f(a4.w + bcol[n4]));
                    *(uint2*)&sU[col * 40 + rbase] = make_uint2(lo, hi);
                }
            }

            // hub GEMM slice: hacc += onehot^T @ U
            short8 aS[4];
            #pragma unroll
            for (int mt = 0; mt < 4; ++mt)
                aS[mt] = *(const short8*)&sOne[p][(mt * 16 + c_lo) * 136 + ks * 32 + c_hi * 8];
            short8 bU[2];
            #pragma unroll
            for (int n4 = 0; n4 < 2; ++n4)
                bU[n4] = *(const short8*)&sU[(wcb + n4 * 16 + c_lo) * 40 + c_hi * 8];
            #pragma unroll
            for (int mt = 0; mt < 4; ++mt)
                #pragma unroll
                for (int n4 = 0; n4 < 2; ++n4)
                    hacc[mt][n4] = __builtin_amdgcn_mfma_f32_16x16x32_bf16(aS[mt], bU[n4], hacc[mt][n4], 0, 0, 0);
        }
        // no trailing barrier: next stage touches only parity (t+1)&1 buffers,
        // fenced against compute(t-1) by this tile's barrier.
    }

    // flush: hub = mt*16 + c_hi*4 + reg, col = wcb + n4*16 + c_lo
    #pragma unroll
    for (int mt = 0; mt < 4; ++mt)
        #pragma unroll
        for (int n4 = 0; n4 < 2; ++n4) {
            float4v v = hacc[mt][n4];
            int col = wcb + n4 * 16 + c_lo;
            #pragma unroll
            for (int reg = 0; reg < 4; ++reg) {
                int hub = mt * 16 + c_hi * 4 + reg;
                size_t o = ((size_t)g * NH + hub) * DIM2 + col;
                if (atomic_mode) atomicAdd(&outbuf[o], v[reg]);
                else outbuf[(size_t)cchunk * BH * DIM2 + o] = v[reg];
            }
        }
}

// ---------- hub_features = (hubsum@W2 + cnt*b2) / max(cnt,1) ----------
__global__ void hubfeat_kernel(const float* __restrict__ part, int nchunk,
                               const int* __restrict__ cnt,
                               const float* __restrict__ W2, const float* __restrict__ b2,
                               float* __restrict__ out) {
    __shared__ float sSum[16 * 256];
    int tid = threadIdx.x;
    int d   = tid & 127;
    int hh  = tid >> 7;

    for (int i = tid; i < 16 * 256; i += 256) {
        size_t o = (size_t)(blockIdx.x * 16) * DIM2 + i;
        float v = 0.f;
        for (int c = 0; c < nchunk; ++c) v += part[(size_t)c * BH * DIM2 + o];
        sSum[i] = v;
    }
    __syncthreads();

    int h0 = hh * 8;
    float acc[8] = {0.f, 0.f, 0.f, 0.f, 0.f, 0.f, 0.f, 0.f};
    for (int k4 = 0; k4 < 64; ++k4) {
        float w0 = W2[(k4 * 4 + 0) * DIM + d];
        float w1 = W2[(k4 * 4 + 1) * DIM + d];
        float w2 = W2[(k4 * 4 + 2) * DIM + d];
        float w3 = W2[(k4 * 4 + 3) * DIM + d];
        #pragma unroll
        for (int j = 0; j < 8; ++j) {
            float4v sv = *(const float4v*)&sSum[(h0 + j) * 256 + k4 * 4];
            acc[j] += sv.x * w0 + sv.y * w1 + sv.z * w2 + sv.w * w3;
        }
    }
    float b2d = b2[d];
    #pragma unroll
    for (int j = 0; j < 8; ++j) {
        int h = blockIdx.x * 16 + h0 + j;
        float c = (float)cnt[h];
        out[OUT_HF + h * DIM + d] = (acc[j] + c * b2d) / fmaxf(c, 1.0f);
    }
}

// ---------- per-graph KNN + edge emission (merged) ----------
__global__ void knn_edges(const float* __restrict__ hf, const int* __restrict__ goff,
                          const int* __restrict__ hubidx, float* __restrict__ out) {
    __shared__ float s[64 * 129];
    __shared__ float d2[64 * 64];
    __shared__ int sK[64 * 4];
    int g = blockIdx.x, tid = threadIdx.x;

    for (int i = tid; i < 64 * 128; i += 256) {
        int r = i >> 7, c = i & 127;
        s[r * 129 + c] = hf[OUT_HF + (g * 64 + r) * DIM + c];
    }
    __syncthreads();

    for (int p = tid; p < 4096; p += 256) {
        int i = p >> 6, j = p & 63;
        float a = 0.f;
        for (int k = 0; k < 128; ++k) {
            float dd = s[i * 129 + k] - s[j * 129 + k];
            a += dd * dd;
        }
        d2[p] = a;
    }
    __syncthreads();

    if (tid < 64) {
        float bv0 = 1e30f, bv1 = 1e30f, bv2 = 1e30f, bv3 = 1e30f;
        int   bi0 = 0,     bi1 = 0,     bi2 = 0,     bi3 = 0;
        for (int j = 0; j < 64; ++j) {
            float v = d2[tid * 64 + j];
            if (v < bv0)      { bv3=bv2; bi3=bi2; bv2=bv1; bi2=bi1; bv1=bv0; bi1=bi0; bv0=v; bi0=j; }
            else if (v < bv1) { bv3=bv2; bi3=bi2; bv2=bv1; bi2=bi1; bv1=v;   bi1=j; }
            else if (v < bv2) { bv3=bv2; bi3=bi2; bv2=v;   bi2=j; }
            else if (v < bv3) { bv3=v;   bi3=j; }
        }
        sK[tid * 4 + 0] = bi0; sK[tid * 4 + 1] = bi1;
        sK[tid * 4 + 2] = bi2; sK[tid * 4 + 3] = bi3;
    }
    __syncthreads();

    int sgs = goff[g], sge = goff[g + 1];
    float gbase = (float)(g * NH);
    for (int i = sgs + tid; i < sge; i += 256) {
        int h = hubidx[i];
        int4 kn = *(const int4*)&sK[h * 4];
        float fi = (float)i;
        float4v o0 = { fi, fi, fi, fi };
        ((float4v*)(out + OUT_E0))[i] = o0;
        float4v o1 = { kn.x + gbase, kn.y + gbase, kn.z + gbase, kn.w + gbase };
        ((float4v*)(out + OUT_E1))[i] = o1;
    }
}

extern "C" void kernel_launch(void* const* d_in, const int* in_sizes, int n_in,
                              void* d_out, int out_size, void* d_ws, size_t ws_size,
                              hipStream_t stream) {
    const float* x        = (const float*)d_in[0];
    const int*   hubidx   = (const int*)d_in[1];
    const int*   batchidx = (const int*)d_in[2];
    const float* W1       = (const float*)d_in[3];
    const float* b1       = (const float*)d_in[4];
    const float* W2       = (const float*)d_in[5];
    const float* b2       = (const float*)d_in[6];
    float* out = (float*)d_out;
    char*  ws  = (char*)d_ws;

    // 2-partial mode: 2 x 8MB part + cnt + w1t + goff
    const size_t need_partial = 16879616;
    int atomic_mode = (ws_size < need_partial) ? 1 : 0;

    float*          part;
    int*            cnt;
    unsigned short* w1t;
    int*            goff;
    if (!atomic_mode) {
        part = (float*)ws;                          // 16777216 B (2 x 8MB)
        cnt  = (int*)(ws + 16777216);               // 32768 B
        w1t  = (unsigned short*)(ws + 16809984);    // 65536 B
        goff = (int*)(ws + 16875520);               // 2048 B
    } else {
        part = (float*)ws;                          // 8388608 B
        cnt  = (int*)(ws + 8388608);
        w1t  = (unsigned short*)(ws + 8421376);
        goff = (int*)(ws + 8486912);
    }

    (void)hipMemsetAsync(cnt, 0, 32768, stream);
    if (atomic_mode) (void)hipMemsetAsync(part, 0, 8388608, stream);

    setup_kernel<<<2176, 256, 0, stream>>>(batchidx, hubidx, W1, w1t, goff, cnt);
    ffn_fused   <<<256,  512, 0, stream>>>(x, hubidx, goff, w1t, b1, part, atomic_mode);
    hubfeat_kernel<<<512, 256, 0, stream>>>(part, atomic_mode ? 1 : 2, cnt, W2, b2, out);
    knn_edges   <<<NB,   256, 0, stream>>>(out, goff, hubidx, out);
}

// Round 5
// 470.682 us; speedup vs baseline: 1.1787x; 1.0469x over previous
//
#include <hip/hip_runtime.h>
#include <hip/hip_bf16.h>

#define N_SPOKES 524288
#define DIM      128
#define DIM2     256
#define NB       128
#define NH       64
#define BH       8192   // NB*NH

// d_out layout (all float32): [0,1048576) hub_features [8192][128]
//                             [1048576, +2097152) spokes_idx row
//                             [3145728, +2097152) hub ids row
#define OUT_HF   0
#define OUT_E0   1048576
#define OUT_E1   3145728

typedef __attribute__((ext_vector_type(8))) short  short8;
typedef __attribute__((ext_vector_type(4))) float  float4v;
typedef __attribute__((ext_vector_type(4))) unsigned short ushort4v;

__device__ inline unsigned short f2bf(float f) {
    __hip_bfloat16 h = __float2bfloat16(f);
    return *reinterpret_cast<unsigned short*>(&h);
}

// packed f32x2 -> bf16x2 (v_cvt_pk_bf16_f32)
__device__ inline unsigned int pkbf(float a, float b) {
    __hip_bfloat162 h = __float22bfloat162_rn(make_float2(a, b));
    union { __hip_bfloat162 h; unsigned int u; } cv;
    cv.h = h;
    return cv.u;
}

// tanh-approx GELU via sigmoid identity
__device__ inline float gelu_f(float v) {
    float s = v * (1.0f + 0.044715f * v * v);
    float e = __builtin_exp2f(-2.302118131f * s);
    return v * __builtin_amdgcn_rcpf(1.0f + e);
}

// ---------- setup: goff + count + W1^T bf16 prep, one kernel ----------
__global__ void setup_kernel(const int* __restrict__ batchidx, const int* __restrict__ hubidx,
                             const float* __restrict__ W1,
                             unsigned short* __restrict__ w1t,
                             int* __restrict__ goff, int* __restrict__ cnt) {
    int b = blockIdx.x, tid = threadIdx.x;
    if (b < 2048) {
        int i = b * 256 + tid;
        if (i < N_SPOKES) {
            int bi = batchidx[i];
            int bp = (i == 0) ? -1 : batchidx[i - 1];
            for (int g = bp + 1; g <= bi; ++g) goff[g] = i;
            if (i == N_SPOKES - 1)
                for (int g = bi + 1; g <= NB; ++g) goff[g] = N_SPOKES;
            atomicAdd(&cnt[bi * NH + hubidx[i]], 1);
        }
    } else {
        int idx = (b - 2048) * 256 + tid;   // 128 blocks -> 32768
        if (idx < DIM * DIM2) {
            int n = idx >> 7, k = idx & 127;
            w1t[idx] = f2bf(W1[k * DIM2 + n]);
        }
    }
}

// ---------- fused FFN + scatter-as-GEMM ----------
// 256 blocks = 128 graphs x 2 chunks, 1024 threads (16 waves), 1 block/CU.
// LDS 124928 B; 16 waves/CU = 4 waves/SIMD (r4 had 2 -- the latency-coverage
// fix that round 2 attempted but lost to spills at 512thr/128reg).
// Per-wave state halves at 16 U-cols/wave: bfr[4]=16 + ld[4]=16 + hacc[4]=16
// + acc[2]=8 + temps ~= 92 regs <= the 128-reg cap of (1024,4): no spill.
// Pipeline: stage(p=t&1) -> barrier -> issue loads(t+1) (in flight across the
// whole compute phase; a pre-barrier issue would be killed by the compiler's
// vmcnt(0) drain) -> compute 4 ks-slices from sA[p]/sOne[p].
__launch_bounds__(1024, 4)
__global__ void ffn_fused(const float* __restrict__ x,
                          const int* __restrict__ hubidx,
                          const int* __restrict__ goff,
                          const unsigned short* __restrict__ w1t,
                          const float* __restrict__ b1,
                          float* __restrict__ outbuf,
                          int atomic_mode) {
    __shared__ unsigned short sA[2][128 * 136];    // 2 x 34816 B  bf16 x tile
    __shared__ unsigned short sU[256 * 40];        // 20480 B  bf16 U^T slice
    __shared__ unsigned short sOne[2][64 * 136];   // 2 x 17408 B  one-hot

    const int tid  = threadIdx.x;
    const int lane = tid & 63;
    const int w    = tid >> 6;          // 0..15
    const int c_lo = lane & 15;
    const int c_hi = lane >> 4;
    const int wcb  = w * 16;            // wave column base (16 cols/wave)
    const int g      = blockIdx.x >> 1;
    const int cchunk = blockIdx.x & 1;

    const int s = goff[g], e = goff[g + 1];
    const int len = e - s;
    const int cs  = (len + 1) >> 1;
    const int ms  = s + cchunk * cs;
    int me = ms + cs; if (me > e) me = e;
    const int n  = me - ms;
    const int nt = (n > 0) ? ((n + 127) >> 7) : 0;

    // W1^T fragments + bias (wave-private cols, L1-resident)
    const int col = wcb + c_lo;
    short8 bfr[4];
    #pragma unroll
    for (int k = 0; k < 4; ++k)
        bfr[k] = *(const short8*)(w1t + col * DIM + k * 32 + c_hi * 8);
    const float bcol = b1[col];

    // hub accumulator [64 hubs x 16 wave-cols] in fp32 C-regs
    float4v hacc[4];
    #pragma unroll
    for (int mt = 0; mt < 4; ++mt) hacc[mt] = (float4v){0.f, 0.f, 0.f, 0.f};

    // zero both one-hot buffers' used region [64][128]
    for (int i = tid; i < 4096; i += 1024) {
        int b = i >> 11, r = (i >> 5) & 63, c = i & 31;
        *(unsigned long long*)&sOne[b][r * 136 + c * 4] = 0ULL;
    }

    const float4v* x4 = (const float4v*)x;

    float4v ld[4];
    int hub_nxt = -1;
    int hubA = -1, hubB = -1;   // hub scattered most recently into parity 0 / 1
    if (nt > 0) {
        #pragma unroll
        for (int it = 0; it < 4; ++it) {
            int f = it * 1024 + tid;
            int r = f >> 5;
            int rr = r < n ? r : n - 1;
            ld[it] = x4[(size_t)(ms + rr) * 32 + (f & 31)];
        }
        if (tid < 128) hub_nxt = (tid < n) ? hubidx[ms + tid] : -1;
    }
    __syncthreads();   // sOne zeroing complete

    for (int t = 0; t < nt; ++t) {
        const int p = t & 1;
        const int hub_cur = hub_nxt;
        const int hclear  = p ? hubB : hubA;

        // ---- stage phase into parity-p buffers ----
        if (tid < 128) {
            if (hclear >= 0)  sOne[p][hclear * 136 + tid] = 0;
            if (hub_cur >= 0) sOne[p][hub_cur * 136 + tid] = (unsigned short)0x3F80;
        }
        if (p) hubB = hub_cur; else hubA = hub_cur;

        #pragma unroll
        for (int it = 0; it < 4; ++it) {
            int f = it * 1024 + tid;
            int row = f >> 5, c4 = f & 31;
            float4v v = ld[it];
            unsigned int lo = pkbf(v.x, v.y);
            unsigned int hi = pkbf(v.z, v.w);
            *(uint2*)&sA[p][row * 136 + c4 * 4] = make_uint2(lo, hi);
        }
        __syncthreads();

        // ---- issue next tile's loads (AFTER barrier: in flight across compute) ----
        if (t + 1 < nt) {
            #pragma unroll
            for (int it = 0; it < 4; ++it) {
                int f = it * 1024 + tid;
                int r = (t + 1) * 128 + (f >> 5);
                int rr = r < n ? r : n - 1;
                ld[it] = x4[(size_t)(ms + rr) * 32 + (f & 31)];
            }
            if (tid < 128) {
                int r = (t + 1) * 128 + tid;
                hub_nxt = (r < n) ? hubidx[ms + r] : -1;
            }
        }

        // ---- compute: 4 ks-slices of 32 spokes each ----
        #pragma unroll
        for (int ks = 0; ks < 4; ++ks) {
            // main GEMM slice: U[32 spokes][16 wave-cols]
            float4v acc[2];
            acc[0] = (float4v){0.f, 0.f, 0.f, 0.f};
            acc[1] = (float4v){0.f, 0.f, 0.f, 0.f};

            #pragma unroll
            for (int k = 0; k < 4; ++k)
                #pragma unroll
                for (int m2 = 0; m2 < 2; ++m2) {
                    short8 a = *(const short8*)&sA[p][(ks * 32 + m2 * 16 + c_lo) * 136 + k * 32 + c_hi * 8];
                    acc[m2] = __builtin_amdgcn_mfma_f32_16x16x32_bf16(a, bfr[k], acc[m2], 0, 0, 0);
                }

            // epilogue: +b1, gelu, packed-cvt, write bf16 U^T slice (wave-private col)
            #pragma unroll
            for (int m2 = 0; m2 < 2; ++m2) {
                int rbase = m2 * 16 + c_hi * 4;
                float4v a4 = acc[m2];
                unsigned int lo = pkbf(gelu_f(a4.x + bcol), gelu_f(a4.y + bcol));
                unsigned int hi = pkbf(gelu_f(a4.z + bcol), gelu_f(a4.w + bcol));
                *(uint2*)&sU[col * 40 + rbase] = make_uint2(lo, hi);
            }

            // hub GEMM slice: hacc += onehot^T @ U
            short8 aS[4];
            #pragma unroll
            for (int mt = 0; mt < 4; ++mt)
                aS[mt] = *(const short8*)&sOne[p][(mt * 16 + c_lo) * 136 + ks * 32 + c_hi * 8];
            short8 bU = *(const short8*)&sU[col * 40 + c_hi * 8];
            #pragma unroll
            for (int mt = 0; mt < 4; ++mt)
                hacc[mt] = __builtin_amdgcn_mfma_f32_16x16x32_bf16(aS[mt], bU, hacc[mt], 0, 0, 0);
        }
        // no trailing barrier: next stage touches only parity (t+1)&1 buffers,
        // fenced against compute(t-1) by this tile's barrier.
    }

    // flush: hub = mt*16 + c_hi*4 + reg, col = wcb + c_lo
    #pragma unroll
    for (int mt = 0; mt < 4; ++mt) {
        float4v v = hacc[mt];
        #pragma unroll
        for (int reg = 0; reg < 4; ++reg) {
            int hub = mt * 16 + c_hi * 4 + reg;
            size_t o = ((size_t)g * NH + hub) * DIM2 + col;
            if (atomic_mode) atomicAdd(&outbuf[o], v[reg]);
            else outbuf[(size_t)cchunk * BH * DIM2 + o] = v[reg];
        }
    }
}

// ---------- hub_features = (hubsum@W2 + cnt*b2) / max(cnt,1) ----------
__global__ void hubfeat_kernel(const float* __restrict__ part, int nchunk,
                               const int* __restrict__ cnt,
                               const float* __restrict__ W2, const float* __restrict__ b2,
                               float* __restrict__ out) {
    __shared__ float sSum[16 * 256];
    int tid = threadIdx.x;
    int d   = tid & 127;
    int hh  = tid >> 7;

    for (int i = tid; i < 16 * 256; i += 256) {
        size_t o = (size_t)(blockIdx.x * 16) * DIM2 + i;
        float v = 0.f;
        for (int c = 0; c < nchunk; ++c) v += part[(size_t)c * BH * DIM2 + o];
        sSum[i] = v;
    }
    __syncthreads();

    int h0 = hh * 8;
    float acc[8] = {0.f, 0.f, 0.f, 0.f, 0.f, 0.f, 0.f, 0.f};
    for (int k4 = 0; k4 < 64; ++k4) {
        float w0 = W2[(k4 * 4 + 0) * DIM + d];
        float w1 = W2[(k4 * 4 + 1) * DIM + d];
        float w2 = W2[(k4 * 4 + 2) * DIM + d];
        float w3 = W2[(k4 * 4 + 3) * DIM + d];
        #pragma unroll
        for (int j = 0; j < 8; ++j) {
            float4v sv = *(const float4v*)&sSum[(h0 + j) * 256 + k4 * 4];
            acc[j] += sv.x * w0 + sv.y * w1 + sv.z * w2 + sv.w * w3;
        }
    }
    float b2d = b2[d];
    #pragma unroll
    for (int j = 0; j < 8; ++j) {
        int h = blockIdx.x * 16 + h0 + j;
        float c = (float)cnt[h];
        out[OUT_HF + h * DIM + d] = (acc[j] + c * b2d) / fmaxf(c, 1.0f);
    }
}

// ---------- per-graph KNN + edge emission (merged) ----------
// d2 via 4x4 register tiles + float4 LDS reads: 8 ds_read_b128 per 16 pairs
// per k-chunk (16x fewer LDS instructions than the scalar version).
// j-tiles strided by 16 so a wave's 16 distinct row addresses spread banks.
__global__ void knn_edges(const float* __restrict__ hf, const int* __restrict__ goff,
                          const int* __restrict__ hubidx, float* __restrict__ out) {
    __shared__ float s[64 * 132];    // 33792 B, stride 132 floats (16B-aligned rows)
    __shared__ float d2[64 * 64];
    __shared__ int sK[64 * 4];
    int g = blockIdx.x, tid = threadIdx.x;

    for (int i = tid; i < 2048; i += 256) {
        int r = i >> 5, c4 = i & 31;
        *(float4v*)&s[r * 132 + c4 * 4] =
            *(const float4v*)&hf[OUT_HF + (g * 64 + r) * DIM + c4 * 4];
    }
    __syncthreads();

    {
        int i0 = (tid >> 4) * 4;    // 16 i-groups of 4 rows
        int j0 = tid & 15;          // j columns {j0, j0+16, j0+32, j0+48}
        float acc[4][4];
        #pragma unroll
        for (int a = 0; a < 4; ++a)
            #pragma unroll
            for (int b = 0; b < 4; ++b) acc[a][b] = 0.f;

        for (int kc = 0; kc < 32; ++kc) {
            float4v ai[4], bj[4];
            #pragma unroll
            for (int a = 0; a < 4; ++a) ai[a] = *(const float4v*)&s[(i0 + a) * 132 + kc * 4];
            #pragma unroll
            for (int b = 0; b < 4; ++b) bj[b] = *(const float4v*)&s[(j0 + b * 16) * 132 + kc * 4];
            #pragma unroll
            for (int a = 0; a < 4; ++a)
                #pragma unroll
                for (int b = 0; b < 4; ++b) {
                    float d0 = ai[a].x - bj[b].x;
                    float d1 = ai[a].y - bj[b].y;
                    float dz = ai[a].z - bj[b].z;
                    float d3 = ai[a].w - bj[b].w;
                    acc[a][b] += d0 * d0 + d1 * d1 + dz * dz + d3 * d3;
                }
        }
        #pragma unroll
        for (int a = 0; a < 4; ++a)
            #pragma unroll
            for (int b = 0; b < 4; ++b)
                d2[(i0 + a) * 64 + j0 + b * 16] = acc[a][b];
    }
    __syncthreads();

    if (tid < 64) {
        float bv0 = 1e30f, bv1 = 1e30f, bv2 = 1e30f, bv3 = 1e30f;
        int   bi0 = 0,     bi1 = 0,     bi2 = 0,     bi3 = 0;
        for (int j = 0; j < 64; ++j) {
            float v = d2[tid * 64 + j];
            if (v < bv0)      { bv3=bv2; bi3=bi2; bv2=bv1; bi2=bi1; bv1=bv0; bi1=bi0; bv0=v; bi0=j; }
            else if (v < bv1) { bv3=bv2; bi3=bi2; bv2=bv1; bi2=bi1; bv1=v;   bi1=j; }
            else if (v < bv2) { bv3=bv2; bi3=bi2; bv2=v;   bi2=j; }
            else if (v < bv3) { bv3=v;   bi3=j; }
        }
        sK[tid * 4 + 0] = bi0; sK[tid * 4 + 1] = bi1;
        sK[tid * 4 + 2] = bi2; sK[tid * 4 + 3] = bi3;
    }
    __syncthreads();

    int sgs = goff[g], sge = goff[g + 1];
    float gbase = (float)(g * NH);
    for (int i = sgs + tid; i < sge; i += 256) {
        int h = hubidx[i];
        int4 kn = *(const int4*)&sK[h * 4];
        float fi = (float)i;
        float4v o0 = { fi, fi, fi, fi };
        ((float4v*)(out + OUT_E0))[i] = o0;
        float4v o1 = { kn.x + gbase, kn.y + gbase, kn.z + gbase, kn.w + gbase };
        ((float4v*)(out + OUT_E1))[i] = o1;
    }
}

extern "C" void kernel_launch(void* const* d_in, const int* in_sizes, int n_in,
                              void* d_out, int out_size, void* d_ws, size_t ws_size,
                              hipStream_t stream) {
    const float* x        = (const float*)d_in[0];
    const int*   hubidx   = (const int*)d_in[1];
    const int*   batchidx = (const int*)d_in[2];
    const float* W1       = (const float*)d_in[3];
    const float* b1       = (const float*)d_in[4];
    const float* W2       = (const float*)d_in[5];
    const float* b2       = (const float*)d_in[6];
    float* out = (float*)d_out;
    char*  ws  = (char*)d_ws;

    // 2-partial mode: 2 x 8MB part + cnt + w1t + goff
    const size_t need_partial = 16879616;
    int atomic_mode = (ws_size < need_partial) ? 1 : 0;

    float*          part;
    int*            cnt;
    unsigned short* w1t;
    int*            goff;
    if (!atomic_mode) {
        part = (float*)ws;                          // 16777216 B (2 x 8MB)
        cnt  = (int*)(ws + 16777216);               // 32768 B
        w1t  = (unsigned short*)(ws + 16809984);    // 65536 B
        goff = (int*)(ws + 16875520);               // 2048 B
    } else {
        part = (float*)ws;                          // 8388608 B
        cnt  = (int*)(ws + 8388608);
        w1t  = (unsigned short*)(ws + 8421376);
        goff = (int*)(ws + 8486912);
    }

    (void)hipMemsetAsync(cnt, 0, 32768, stream);
    if (atomic_mode) (void)hipMemsetAsync(part, 0, 8388608, stream);

    setup_kernel<<<2176, 256, 0, stream>>>(batchidx, hubidx, W1, w1t, goff, cnt);
    ffn_fused   <<<256, 1024, 0, stream>>>(x, hubidx, goff, w1t, b1, part, atomic_mode);
    hubfeat_kernel<<<512, 256, 0, stream>>>(part, atomic_mode ? 1 : 2, cnt, W2, b2, out);
    knn_edges   <<<NB,   256, 0, stream>>>(out, goff, hubidx, out);
}

// Round 7
// 465.805 us; speedup vs baseline: 1.1911x; 1.0105x over previous
//
#include <hip/hip_runtime.h>
#include <hip/hip_bf16.h>

#define N_SPOKES 524288
#define DIM      128
#define DIM2     256
#define NB       128
#define NH       64
#define BH       8192   // NB*NH

// d_out layout (all float32): [0,1048576) hub_features [8192][128]
//                             [1048576, +2097152) spokes_idx row
//                             [3145728, +2097152) hub ids row
#define OUT_HF   0
#define OUT_E0   1048576
#define OUT_E1   3145728

typedef __attribute__((ext_vector_type(8))) short  short8;
typedef __attribute__((ext_vector_type(4))) float  float4v;
typedef __attribute__((ext_vector_type(4))) unsigned short ushort4v;

__device__ inline unsigned short f2bf(float f) {
    __hip_bfloat16 h = __float2bfloat16(f);
    return *reinterpret_cast<unsigned short*>(&h);
}

// packed f32x2 -> bf16x2 (v_cvt_pk_bf16_f32)
__device__ inline unsigned int pkbf(float a, float b) {
    __hip_bfloat162 h = __float22bfloat162_rn(make_float2(a, b));
    union { __hip_bfloat162 h; unsigned int u; } cv;
    cv.h = h;
    return cv.u;
}

// tanh-approx GELU via sigmoid identity
__device__ inline float gelu_f(float v) {
    float s = v * (1.0f + 0.044715f * v * v);
    float e = __builtin_exp2f(-2.302118131f * s);
    return v * __builtin_amdgcn_rcpf(1.0f + e);
}

// ---------- setup: goff + count + W1^T bf16 prep, one kernel ----------
__global__ void setup_kernel(const int* __restrict__ batchidx, const int* __restrict__ hubidx,
                             const float* __restrict__ W1,
                             unsigned short* __restrict__ w1t,
                             int* __restrict__ goff, int* __restrict__ cnt) {
    int b = blockIdx.x, tid = threadIdx.x;
    if (b < 2048) {
        int i = b * 256 + tid;
        if (i < N_SPOKES) {
            int bi = batchidx[i];
            int bp = (i == 0) ? -1 : batchidx[i - 1];
            for (int g = bp + 1; g <= bi; ++g) goff[g] = i;
            if (i == N_SPOKES - 1)
                for (int g = bi + 1; g <= NB; ++g) goff[g] = N_SPOKES;
            atomicAdd(&cnt[bi * NH + hubidx[i]], 1);
        }
    } else {
        int idx = (b - 2048) * 256 + tid;   // 128 blocks -> 32768
        if (idx < DIM * DIM2) {
            int n = idx >> 7, k = idx & 127;
            w1t[idx] = f2bf(W1[k * DIM2 + n]);
        }
    }
}

// ---------- fused FFN + scatter-as-GEMM ----------
// 256 blocks = 128 graphs x 2 chunks, 1024 threads (16 waves), 1 block/CU,
// 4 waves/SIMD.  LDS 145408 B (sA[2], sU[2], sOne[2]).
// The hub GEMM LAGS one ks-slice behind the main GEMM: previously each ks ran
// the serial chain main-MFMA -> gelu -> ds_write sU -> ds_read bU -> lgkm wait
// -> hub-MFMA (latency exposed 64x per tile per block).  sU columns are
// wave-private, so double-buffering the slice and deferring hub(ks-1) into
// iteration ks removes the chain with NO sync cost: the bU read overlaps the
// next slice's main MFMA + gelu.
// Bias is folded into the MFMA C initializer (column-constant -> the whole
// C fragment of a lane shares one bias value): deletes 32 v_add/thread/tile.
// Pipeline: stage(p=t&1) -> barrier -> issue loads(t+1) (in flight across
// compute; pre-barrier issue would be killed by the vmcnt(0) drain) ->
// compute 4 ks-slices from sA[p]/sOne[p].
__launch_bounds__(1024, 4)
__global__ void ffn_fused(const float* __restrict__ x,
                          const int* __restrict__ hubidx,
                          const int* __restrict__ goff,
                          const unsigned short* __restrict__ w1t,
                          const float* __restrict__ b1,
                          float* __restrict__ outbuf,
                          int atomic_mode) {
    __shared__ unsigned short sA[2][128 * 136];    // 2 x 34816 B  bf16 x tile
    __shared__ unsigned short sU[2][256 * 40];     // 2 x 20480 B  bf16 U^T slice
    __shared__ unsigned short sOne[2][64 * 136];   // 2 x 17408 B  one-hot

    const int tid  = threadIdx.x;
    const int lane = tid & 63;
    const int w    = tid >> 6;          // 0..15
    const int c_lo = lane & 15;
    const int c_hi = lane >> 4;
    const int wcb  = w * 16;            // wave column base (16 cols/wave)
    const int g      = blockIdx.x >> 1;
    const int cchunk = blockIdx.x & 1;

    const int s = goff[g], e = goff[g + 1];
    const int len = e - s;
    const int cs  = (len + 1) >> 1;
    const int ms  = s + cchunk * cs;
    int me = ms + cs; if (me > e) me = e;
    const int n  = me - ms;
    const int nt = (n > 0) ? ((n + 127) >> 7) : 0;

    // W1^T fragments + bias (wave-private cols, L1-resident)
    const int col = wcb + c_lo;
    short8 bfr[4];
    #pragma unroll
    for (int k = 0; k < 4; ++k)
        bfr[k] = *(const short8*)(w1t + col * DIM + k * 32 + c_hi * 8);
    const float bcol = b1[col];

    // hub accumulator [64 hubs x 16 wave-cols] in fp32 C-regs
    float4v hacc[4];
    #pragma unroll
    for (int mt = 0; mt < 4; ++mt) hacc[mt] = (float4v){0.f, 0.f, 0.f, 0.f};

    // zero both one-hot buffers' used region [64][128]
    for (int i = tid; i < 4096; i += 1024) {
        int b = i >> 11, r = (i >> 5) & 63, c = i & 31;
        *(unsigned long long*)&sOne[b][r * 136 + c * 4] = 0ULL;
    }

    const float4v* x4 = (const float4v*)x;

    float4v ld[4];
    int hub_nxt = -1;
    int hubA = -1, hubB = -1;   // hub scattered most recently into parity 0 / 1
    if (nt > 0) {
        #pragma unroll
        for (int it = 0; it < 4; ++it) {
            int f = it * 1024 + tid;
            int r = f >> 5;
            int rr = r < n ? r : n - 1;
            ld[it] = x4[(size_t)(ms + rr) * 32 + (f & 31)];
        }
        if (tid < 128) hub_nxt = (tid < n) ? hubidx[ms + tid] : -1;
    }
    __syncthreads();   // sOne zeroing complete

    for (int t = 0; t < nt; ++t) {
        const int p = t & 1;
        const int hub_cur = hub_nxt;
        const int hclear  = p ? hubB : hubA;

        // ---- stage phase into parity-p buffers ----
        if (tid < 128) {
            if (hclear >= 0)  sOne[p][hclear * 136 + tid] = 0;
            if (hub_cur >= 0) sOne[p][hub_cur * 136 + tid] = (unsigned short)0x3F80;
        }
        if (p) hubB = hub_cur; else hubA = hub_cur;

        #pragma unroll
        for (int it = 0; it < 4; ++it) {
            int f = it * 1024 + tid;
            int row = f >> 5, c4 = f & 31;
            float4v v = ld[it];
            unsigned int lo = pkbf(v.x, v.y);
            unsigned int hi = pkbf(v.z, v.w);
            *(uint2*)&sA[p][row * 136 + c4 * 4] = make_uint2(lo, hi);
        }
        __syncthreads();

        // ---- issue next tile's loads (AFTER barrier: in flight across compute) ----
        if (t + 1 < nt) {
            #pragma unroll
            for (int it = 0; it < 4; ++it) {
                int f = it * 1024 + tid;
                int r = (t + 1) * 128 + (f >> 5);
                int rr = r < n ? r : n - 1;
                ld[it] = x4[(size_t)(ms + rr) * 32 + (f & 31)];
            }
            if (tid < 128) {
                int r = (t + 1) * 128 + tid;
                hub_nxt = (r < n) ? hubidx[ms + r] : -1;
            }
        }

        // ---- compute: 4 ks-slices; hub GEMM lags one slice ----
        #pragma unroll
        for (int ks = 0; ks < 4; ++ks) {
            // main GEMM slice: U[32 spokes][16 wave-cols]; C pre-loaded with bias
            float4v acc[2];
            acc[0] = (float4v){bcol, bcol, bcol, bcol};
            acc[1] = acc[0];

            #pragma unroll
            for (int k = 0; k < 4; ++k)
                #pragma unroll
                for (int m2 = 0; m2 < 2; ++m2) {
                    short8 a = *(const short8*)&sA[p][(ks * 32 + m2 * 16 + c_lo) * 136 + k * 32 + c_hi * 8];
                    acc[m2] = __builtin_amdgcn_mfma_f32_16x16x32_bf16(a, bfr[k], acc[m2], 0, 0, 0);
                }

            // hub GEMM for PREVIOUS slice (wave-private sU; no sync needed,
            // read overlaps this slice's main MFMA + gelu)
            if (ks > 0) {
                const int ksp = ks - 1;
                short8 aS[4];
                #pragma unroll
                for (int mt = 0; mt < 4; ++mt)
                    aS[mt] = *(const short8*)&sOne[p][(mt * 16 + c_lo) * 136 + ksp * 32 + c_hi * 8];
                short8 bU = *(const short8*)&sU[ksp & 1][col * 40 + c_hi * 8];
                #pragma unroll
                for (int mt = 0; mt < 4; ++mt)
                    hacc[mt] = __builtin_amdgcn_mfma_f32_16x16x32_bf16(aS[mt], bU, hacc[mt], 0, 0, 0);
            }

            // epilogue: gelu, packed-cvt, write bf16 U^T slice into sU[ks&1]
            #pragma unroll
            for (int m2 = 0; m2 < 2; ++m2) {
                int rbase = m2 * 16 + c_hi * 4;
                float4v a4 = acc[m2];
                unsigned int lo = pkbf(gelu_f(a4.x), gelu_f(a4.y));
                unsigned int hi = pkbf(gelu_f(a4.z), gelu_f(a4.w));
                *(uint2*)&sU[ks & 1][col * 40 + rbase] = make_uint2(lo, hi);
            }
        }
        // drain: hub GEMM for the last slice (ks=3, buffer 1)
        {
            short8 aS[4];
            #pragma unroll
            for (int mt = 0; mt < 4; ++mt)
                aS[mt] = *(const short8*)&sOne[p][(mt * 16 + c_lo) * 136 + 3 * 32 + c_hi * 8];
            short8 bU = *(const short8*)&sU[1][col * 40 + c_hi * 8];
            #pragma unroll
            for (int mt = 0; mt < 4; ++mt)
                hacc[mt] = __builtin_amdgcn_mfma_f32_16x16x32_bf16(aS[mt], bU, hacc[mt], 0, 0, 0);
        }
        // no trailing barrier: next stage touches only parity (t+1)&1 buffers,
        // fenced against compute(t-1) by this tile's barrier.
    }

    // flush: hub = mt*16 + c_hi*4 + reg, col = wcb + c_lo
    #pragma unroll
    for (int mt = 0; mt < 4; ++mt) {
        float4v v = hacc[mt];
        #pragma unroll
        for (int reg = 0; reg < 4; ++reg) {
            int hub = mt * 16 + c_hi * 4 + reg;
            size_t o = ((size_t)g * NH + hub) * DIM2 + col;
            if (atomic_mode) atomicAdd(&outbuf[o], v[reg]);
            else outbuf[(size_t)cchunk * BH * DIM2 + o] = v[reg];
        }
    }
}

// ---------- hub_features = (hubsum@W2 + cnt*b2) / max(cnt,1) ----------
__global__ void hubfeat_kernel(const float* __restrict__ part, int nchunk,
                               const int* __restrict__ cnt,
                               const float* __restrict__ W2, const float* __restrict__ b2,
                               float* __restrict__ out) {
    __shared__ float sSum[16 * 256];
    int tid = threadIdx.x;
    int d   = tid & 127;
    int hh  = tid >> 7;

    // float4 loads of the partial buffers (1024 float4s per block)
    for (int i = tid; i < 1024; i += 256) {
        size_t o = (size_t)(blockIdx.x * 16) * DIM2 + i * 4;
        float4v v = *(const float4v*)&part[o];
        for (int c = 1; c < nchunk; ++c) {
            float4v v2 = *(const float4v*)&part[(size_t)c * BH * DIM2 + o];
            v.x += v2.x; v.y += v2.y; v.z += v2.z; v.w += v2.w;
        }
        *(float4v*)&sSum[i * 4] = v;
    }
    __syncthreads();

    int h0 = hh * 8;
    float acc[8] = {0.f, 0.f, 0.f, 0.f, 0.f, 0.f, 0.f, 0.f};
    for (int k4 = 0; k4 < 64; ++k4) {
        float w0 = W2[(k4 * 4 + 0) * DIM + d];
        float w1 = W2[(k4 * 4 + 1) * DIM + d];
        float w2 = W2[(k4 * 4 + 2) * DIM + d];
        float w3 = W2[(k4 * 4 + 3) * DIM + d];
        #pragma unroll
        for (int j = 0; j < 8; ++j) {
            float4v sv = *(const float4v*)&sSum[(h0 + j) * 256 + k4 * 4];
            acc[j] += sv.x * w0 + sv.y * w1 + sv.z * w2 + sv.w * w3;
        }
    }
    float b2d = b2[d];
    #pragma unroll
    for (int j = 0; j < 8; ++j) {
        int h = blockIdx.x * 16 + h0 + j;
        float c = (float)cnt[h];
        out[OUT_HF + h * DIM + d] = (acc[j] + c * b2d) / fmaxf(c, 1.0f);
    }
}

// ---------- per-graph KNN + edge emission (merged) ----------
// d2 via 4x4 register tiles + float4 LDS reads: 8 ds_read_b128 per 16 pairs
// per k-chunk (16x fewer LDS instructions than the scalar version).
// j-tiles strided by 16 so a wave's 16 distinct row addresses spread banks.
__global__ void knn_edges(const float* __restrict__ hf, const int* __restrict__ goff,
                          const int* __restrict__ hubidx, float* __restrict__ out) {
    __shared__ float s[64 * 132];    // 33792 B, stride 132 floats (16B-aligned rows)
    __shared__ float d2[64 * 64];
    __shared__ int sK[64 * 4];
    int g = blockIdx.x, tid = threadIdx.x;

    for (int i = tid; i < 2048; i += 256) {
        int r = i >> 5, c4 = i & 31;
        *(float4v*)&s[r * 132 + c4 * 4] =
            *(const float4v*)&hf[OUT_HF + (g * 64 + r) * DIM + c4 * 4];
    }
    __syncthreads();

    {
        int i0 = (tid >> 4) * 4;    // 16 i-groups of 4 rows
        int j0 = tid & 15;          // j columns {j0, j0+16, j0+32, j0+48}
        float acc[4][4];
        #pragma unroll
        for (int a = 0; a < 4; ++a)
            #pragma unroll
            for (int b = 0; b < 4; ++b) acc[a][b] = 0.f;

        for (int kc = 0; kc < 32; ++kc) {
            float4v ai[4], bj[4];
            #pragma unroll
            for (int a = 0; a < 4; ++a) ai[a] = *(const float4v*)&s[(i0 + a) * 132 + kc * 4];
            #pragma unroll
            for (int b = 0; b < 4; ++b) bj[b] = *(const float4v*)&s[(j0 + b * 16) * 132 + kc * 4];
            #pragma unroll
            for (int a = 0; a < 4; ++a)
                #pragma unroll
                for (int b = 0; b < 4; ++b) {
                    float d0 = ai[a].x - bj[b].x;
                    float d1 = ai[a].y - bj[b].y;
                    float dz = ai[a].z - bj[b].z;
                    float d3 = ai[a].w - bj[b].w;
                    acc[a][b] += d0 * d0 + d1 * d1 + dz * dz + d3 * d3;
                }
        }
        #pragma unroll
        for (int a = 0; a < 4; ++a)
            #pragma unroll
            for (int b = 0; b < 4; ++b)
                d2[(i0 + a) * 64 + j0 + b * 16] = acc[a][b];
    }
    __syncthreads();

    if (tid < 64) {
        float bv0 = 1e30f, bv1 = 1e30f, bv2 = 1e30f, bv3 = 1e30f;
        int   bi0 = 0,     bi1 = 0,     bi2 = 0,     bi3 = 0;
        for (int j = 0; j < 64; ++j) {
            float v = d2[tid * 64 + j];
            if (v < bv0)      { bv3=bv2; bi3=bi2; bv2=bv1; bi2=bi1; bv1=bv0; bi1=bi0; bv0=v; bi0=j; }
            else if (v < bv1) { bv3=bv2; bi3=bi2; bv2=bv1; bi2=bi1; bv1=v;   bi1=j; }
            else if (v < bv2) { bv3=bv2; bi3=bi2; bv2=v;   bi2=j; }
            else if (v < bv3) { bv3=v;   bi3=j; }
        }
        sK[tid * 4 + 0] = bi0; sK[tid * 4 + 1] = bi1;
        sK[tid * 4 + 2] = bi2; sK[tid * 4 + 3] = bi3;
    }
    __syncthreads();

    int sgs = goff[g], sge = goff[g + 1];
    float gbase = (float)(g * NH);
    for (int i = sgs + tid; i < sge; i += 256) {
        int h = hubidx[i];
        int4 kn = *(const int4*)&sK[h * 4];
        float fi = (float)i;
        float4v o0 = { fi, fi, fi, fi };
        ((float4v*)(out + OUT_E0))[i] = o0;
        float4v o1 = { kn.x + gbase, kn.y + gbase, kn.z + gbase, kn.w + gbase };
        ((float4v*)(out + OUT_E1))[i] = o1;
    }
}

extern "C" void kernel_launch(void* const* d_in, const int* in_sizes, int n_in,
                              void* d_out, int out_size, void* d_ws, size_t ws_size,
                              hipStream_t stream) {
    const float* x        = (const float*)d_in[0];
    const int*   hubidx   = (const int*)d_in[1];
    const int*   batchidx = (const int*)d_in[2];
    const float* W1       = (const float*)d_in[3];
    const float* b1       = (const float*)d_in[4];
    const float* W2       = (const float*)d_in[5];
    const float* b2       = (const float*)d_in[6];
    float* out = (float*)d_out;
    char*  ws  = (char*)d_ws;

    // 2-partial mode: 2 x 8MB part + cnt + w1t + goff
    const size_t need_partial = 16879616;
    int atomic_mode = (ws_size < need_partial) ? 1 : 0;

    float*          part;
    int*            cnt;
    unsigned short* w1t;
    int*            goff;
    if (!atomic_mode) {
        part = (float*)ws;                          // 16777216 B (2 x 8MB)
        cnt  = (int*)(ws + 16777216);               // 32768 B
        w1t  = (unsigned short*)(ws + 16809984);    // 65536 B
        goff = (int*)(ws + 16875520);               // 2048 B
    } else {
        part = (float*)ws;                          // 8388608 B
        cnt  = (int*)(ws + 8388608);
        w1t  = (unsigned short*)(ws + 8421376);
        goff = (int*)(ws + 8486912);
    }

    (void)hipMemsetAsync(cnt, 0, 32768, stream);
    if (atomic_mode) (void)hipMemsetAsync(part, 0, 8388608, stream);

    setup_kernel<<<2176, 256, 0, stream>>>(batchidx, hubidx, W1, w1t, goff, cnt);
    ffn_fused   <<<256, 1024, 0, stream>>>(x, hubidx, goff, w1t, b1, part, atomic_mode);
    hubfeat_kernel<<<512, 256, 0, stream>>>(part, atomic_mode ? 1 : 2, cnt, W2, b2, out);
    knn_edges   <<<NB,   256, 0, stream>>>(out, goff, hubidx, out);
}